// Round 1
// baseline (737.480 us; speedup 1.0000x reference)
//
#include <hip/hip_runtime.h>

#define HEADS 4
#define HID 64
#define HC 256  // HEADS*HID

// ---------------- weight transpose: W [256,F] -> WT [F,256] ----------------
__global__ void transpose_w(const float* __restrict__ W, float* __restrict__ WT, int F) {
  int i = blockIdx.x * blockDim.x + threadIdx.x;
  if (i < HC * F) {
    int r = i / F, k = i - r * F;
    WT[k * HC + r] = W[i];
  }
}

// ---------------- node linear: xl = x@Wl.T, xr = x@Wr.T --------------------
// Block = 256 threads, TN=16 nodes/block. Thread tid owns output column tid
// for both Wl and Wr. x rows staged in LDS (broadcast reads), W reads coalesced.
template <int F>
__global__ __launch_bounds__(256) void gemm_lr(const float* __restrict__ xin,
                                               const float* __restrict__ WlT,
                                               const float* __restrict__ WrT,
                                               float* __restrict__ xl,
                                               float* __restrict__ xr, int n_nodes) {
  constexpr int TN = 16;
  __shared__ float xs[TN][F];
  const int node0 = blockIdx.x * TN;
  const int tid = threadIdx.x;
  for (int i = tid; i < TN * F; i += 256) {
    int j = i / F, k = i - j * F;
    int node = node0 + j;
    xs[j][k] = (node < n_nodes) ? xin[node * F + k] : 0.f;
  }
  __syncthreads();
  float accl[TN], accr[TN];
#pragma unroll
  for (int j = 0; j < TN; ++j) { accl[j] = 0.f; accr[j] = 0.f; }
  for (int k = 0; k < F; ++k) {
    float wl = WlT[k * HC + tid];
    float wr = WrT[k * HC + tid];
#pragma unroll
    for (int j = 0; j < TN; ++j) {
      float xv = xs[j][k];
      accl[j] = fmaf(wl, xv, accl[j]);
      accr[j] = fmaf(wr, xv, accr[j]);
    }
  }
#pragma unroll
  for (int j = 0; j < TN; ++j) {
    int node = node0 + j;
    if (node < n_nodes) {
      xl[node * HC + tid] = accl[j];
      xr[node * HC + tid] = accr[j];
    }
  }
}

// ---------------- edge logits: alpha_unnorm[e,h] = exp(z . att), denom atomics
// One wave per edge. Lane l owns channels 4l..4l+3 (head = l/16, flat att idx = 4l+j).
// e-term recomputed from edge_attr (3 floats) and per-lane We rows.
__global__ __launch_bounds__(256) void edge_logits(
    const float* __restrict__ xl, const float* __restrict__ xr,
    const float* __restrict__ ea, const float* __restrict__ We,
    const float* __restrict__ att, const int* __restrict__ ei,
    float* __restrict__ alpha, float* __restrict__ denom, int E_) {
  const int lane = threadIdx.x & 63;
  const int wave = (blockIdx.x * blockDim.x + threadIdx.x) >> 6;
  const int nwaves = (gridDim.x * blockDim.x) >> 6;
  float we0[4], we1[4], we2[4], at[4];
#pragma unroll
  for (int j = 0; j < 4; ++j) {
    int r = 4 * lane + j;
    we0[j] = We[r * 3 + 0];
    we1[j] = We[r * 3 + 1];
    we2[j] = We[r * 3 + 2];
    at[j] = att[r];
  }
  const float4* xl4 = (const float4*)xl;
  const float4* xr4 = (const float4*)xr;
  for (int e = wave; e < E_; e += nwaves) {
    int src = ei[e];
    int dst = ei[E_ + e];
    float4 la = xl4[src * 64 + lane];
    float4 ra = xr4[dst * 64 + lane];
    float a0 = ea[e * 3 + 0], a1 = ea[e * 3 + 1], a2 = ea[e * 3 + 2];
    float lav[4] = {la.x, la.y, la.z, la.w};
    float rav[4] = {ra.x, ra.y, ra.z, ra.w};
    float p = 0.f;
#pragma unroll
    for (int j = 0; j < 4; ++j) {
      float ev = fmaf(we0[j], a0, fmaf(we1[j], a1, we2[j] * a2));
      float s = lav[j] + rav[j] + ev;
      float z = (s >= 0.f) ? s : 0.2f * s;
      p = fmaf(z, at[j], p);
    }
    // reduce over the 16-lane head group (masks <16 stay inside the group)
    p += __shfl_xor(p, 1);
    p += __shfl_xor(p, 2);
    p += __shfl_xor(p, 4);
    p += __shfl_xor(p, 8);
    if ((lane & 15) == 0) {
      int h = lane >> 4;
      float ex = expf(p);  // no max-subtraction needed: |logit| << 80
      alpha[e * 4 + h] = ex;
      atomicAdd(&denom[dst * 4 + h], ex);
    }
  }
}

// ---------------- edge message: acc[dst,c] += (1/4) sum_h a_h * xl[src,h,c]
// One wave per edge, lane = channel c. Head-mean folded in -> 64 atomics/edge.
__global__ __launch_bounds__(256) void edge_msg(
    const float* __restrict__ xl, const float* __restrict__ alpha,
    const float* __restrict__ denom, const int* __restrict__ ei,
    float* __restrict__ acc, int E_) {
  const int lane = threadIdx.x & 63;
  const int wave = (blockIdx.x * blockDim.x + threadIdx.x) >> 6;
  const int nwaves = (gridDim.x * blockDim.x) >> 6;
  for (int e = wave; e < E_; e += nwaves) {
    int src = ei[e];
    int dst = ei[E_ + e];
    float an[4];
#pragma unroll
    for (int h = 0; h < 4; ++h) {
      an[h] = alpha[e * 4 + h] / (denom[dst * 4 + h] + 1e-16f);
    }
    const float* xs = xl + (size_t)src * HC;
    float v = an[0] * xs[lane] + an[1] * xs[64 + lane] + an[2] * xs[128 + lane] +
              an[3] * xs[192 + lane];
    atomicAdd(&acc[dst * 64 + lane], 0.25f * v);
  }
}

// ---------------- finalize: + bias (and PReLU for layer 2) -----------------
__global__ void finalize(const float* __restrict__ acc, const float* __restrict__ b,
                         float* __restrict__ out, int n) {
  int i = blockIdx.x * blockDim.x + threadIdx.x;
  if (i < n * 64) {
    int c = i & 63;
    out[i] = acc[i] + b[c];
  }
}

__global__ void finalize_prelu(const float* __restrict__ acc, const float* __restrict__ b,
                               const float* __restrict__ pw, float* __restrict__ out, int n) {
  int i = blockIdx.x * blockDim.x + threadIdx.x;
  if (i < n * 64) {
    int c = i & 63;
    float v = acc[i] + b[c];
    out[i] = (v >= 0.f) ? v : pw[c] * v;
  }
}

extern "C" void kernel_launch(void* const* d_in, const int* in_sizes, int n_in,
                              void* d_out, int out_size, void* d_ws, size_t ws_size,
                              hipStream_t stream) {
  const float* x    = (const float*)d_in[0];
  const int*   ei   = (const int*)d_in[1];
  const float* ea   = (const float*)d_in[2];
  const float* Wl1  = (const float*)d_in[3];
  const float* Wr1  = (const float*)d_in[4];
  const float* We1  = (const float*)d_in[5];
  const float* att1 = (const float*)d_in[6];
  const float* b1   = (const float*)d_in[7];
  const float* Wl2  = (const float*)d_in[8];
  const float* Wr2  = (const float*)d_in[9];
  const float* We2  = (const float*)d_in[10];
  const float* att2 = (const float*)d_in[11];
  const float* b2   = (const float*)d_in[12];
  const float* pw   = (const float*)d_in[13];
  const int N_ = in_sizes[0] / 128;
  const int E_ = in_sizes[1] / 2;
  float* out = (float*)d_out;

  char* w = (char*)d_ws;
  auto alloc = [&](size_t bytes) {
    char* p = w;
    w += (bytes + 255) & ~size_t(255);
    return p;
  };
  float* xl    = (float*)alloc((size_t)N_ * HC * 4);
  float* xr    = (float*)alloc((size_t)N_ * HC * 4);
  float* alpha = (float*)alloc((size_t)E_ * 4 * 4);
  float* denom = (float*)alloc((size_t)N_ * 4 * 4);
  float* acc   = (float*)alloc((size_t)N_ * 64 * 4);
  float* hbuf  = (float*)alloc((size_t)N_ * 64 * 4);
  float* WlT1  = (float*)alloc(128 * HC * 4);
  float* WrT1  = (float*)alloc(128 * HC * 4);
  float* WlT2  = (float*)alloc(64 * HC * 4);
  float* WrT2  = (float*)alloc(64 * HC * 4);

  transpose_w<<<(HC * 128 + 255) / 256, 256, 0, stream>>>(Wl1, WlT1, 128);
  transpose_w<<<(HC * 128 + 255) / 256, 256, 0, stream>>>(Wr1, WrT1, 128);
  transpose_w<<<(HC * 64 + 255) / 256, 256, 0, stream>>>(Wl2, WlT2, 64);
  transpose_w<<<(HC * 64 + 255) / 256, 256, 0, stream>>>(Wr2, WrT2, 64);

  const int EB = 2048;  // edge-kernel blocks (8192 waves, grid-stride)
  const int GB = (N_ + 15) / 16;

  // ---------------- layer 1 ----------------
  hipMemsetAsync(denom, 0, (size_t)N_ * 4 * 4, stream);
  hipMemsetAsync(acc, 0, (size_t)N_ * 64 * 4, stream);
  gemm_lr<128><<<GB, 256, 0, stream>>>(x, WlT1, WrT1, xl, xr, N_);
  edge_logits<<<EB, 256, 0, stream>>>(xl, xr, ea, We1, att1, ei, alpha, denom, E_);
  edge_msg<<<EB, 256, 0, stream>>>(xl, alpha, denom, ei, acc, E_);
  finalize<<<(N_ * 64 + 255) / 256, 256, 0, stream>>>(acc, b1, hbuf, N_);

  // ---------------- layer 2 ----------------
  hipMemsetAsync(denom, 0, (size_t)N_ * 4 * 4, stream);
  hipMemsetAsync(acc, 0, (size_t)N_ * 64 * 4, stream);
  gemm_lr<64><<<GB, 256, 0, stream>>>(hbuf, WlT2, WrT2, xl, xr, N_);
  edge_logits<<<EB, 256, 0, stream>>>(xl, xr, ea, We2, att2, ei, alpha, denom, E_);
  edge_msg<<<EB, 256, 0, stream>>>(xl, alpha, denom, ei, acc, E_);
  finalize_prelu<<<(N_ * 64 + 255) / 256, 256, 0, stream>>>(acc, b2, pw, out, N_);
}

// Round 2
// 722.193 us; speedup vs baseline: 1.0212x; 1.0212x over previous
//
#include <hip/hip_runtime.h>

#define HEADS 4
#define HID 64
#define HC 256  // HEADS*HID

// ---------------- weight transpose: W [256,F] -> WT [F,256] ----------------
__global__ void transpose_w(const float* __restrict__ W, float* __restrict__ WT, int F) {
  int i = blockIdx.x * blockDim.x + threadIdx.x;
  if (i < HC * F) {
    int r = i / F, k = i - r * F;
    WT[k * HC + r] = W[i];
  }
}

// ---------------- node linear: xl = x@Wl.T, xr = x@Wr.T --------------------
// Block = 256 threads, TN=16 nodes/block. Thread tid owns output column tid.
// k-loop unrolled x4 with software-pipelined W prefetch; x tile staged in LDS,
// read back as float4 broadcasts (ds_read_b128, same addr across wave).
template <int F>
__global__ __launch_bounds__(256) void gemm_lr(const float* __restrict__ xin,
                                               const float* __restrict__ WlT,
                                               const float* __restrict__ WrT,
                                               float* __restrict__ xl,
                                               float* __restrict__ xr, int n_nodes) {
  constexpr int TN = 16;
  __shared__ float xs[TN][F];
  const int node0 = blockIdx.x * TN;
  const int tid = threadIdx.x;
  if (node0 + TN <= n_nodes) {
    const float4* xin4 = (const float4*)xin;
    float4* xs4 = (float4*)(&xs[0][0]);
    for (int i = tid; i < TN * F / 4; i += 256) {
      xs4[i] = xin4[(size_t)node0 * (F / 4) + i];
    }
  } else {
    for (int i = tid; i < TN * F; i += 256) {
      int j = i / F, k = i - j * F;
      int node = node0 + j;
      xs[j][k] = (node < n_nodes) ? xin[node * F + k] : 0.f;
    }
  }
  __syncthreads();

  float accl[TN], accr[TN];
#pragma unroll
  for (int j = 0; j < TN; ++j) { accl[j] = 0.f; accr[j] = 0.f; }

  // prefetch chunk 0
  float wl[4], wr[4];
#pragma unroll
  for (int u = 0; u < 4; ++u) {
    wl[u] = WlT[u * HC + tid];
    wr[u] = WrT[u * HC + tid];
  }

  for (int k = 0; k < F; k += 4) {
    float nwl[4], nwr[4];
    if (k + 4 < F) {
#pragma unroll
      for (int u = 0; u < 4; ++u) {
        nwl[u] = WlT[(k + 4 + u) * HC + tid];
        nwr[u] = WrT[(k + 4 + u) * HC + tid];
      }
    }
#pragma unroll
    for (int j = 0; j < TN; ++j) {
      float4 xv = *(const float4*)&xs[j][k];
      accl[j] = fmaf(wl[0], xv.x, accl[j]);
      accl[j] = fmaf(wl[1], xv.y, accl[j]);
      accl[j] = fmaf(wl[2], xv.z, accl[j]);
      accl[j] = fmaf(wl[3], xv.w, accl[j]);
      accr[j] = fmaf(wr[0], xv.x, accr[j]);
      accr[j] = fmaf(wr[1], xv.y, accr[j]);
      accr[j] = fmaf(wr[2], xv.z, accr[j]);
      accr[j] = fmaf(wr[3], xv.w, accr[j]);
    }
#pragma unroll
    for (int u = 0; u < 4; ++u) {
      wl[u] = nwl[u];
      wr[u] = nwr[u];
    }
  }

#pragma unroll
  for (int j = 0; j < TN; ++j) {
    int node = node0 + j;
    if (node < n_nodes) {
      xl[node * HC + tid] = accl[j];
      xr[node * HC + tid] = accr[j];
    }
  }
}

// ---------------- edge logits: alpha_unnorm[e,h] = exp(z . att), denom atomics
// One wave per edge; lane l owns channels 4l..4l+3. Next edge's indices and
// edge_attr are prefetched while the current edge's gathers are in flight.
__global__ __launch_bounds__(256) void edge_logits(
    const float* __restrict__ xl, const float* __restrict__ xr,
    const float* __restrict__ ea, const float* __restrict__ We,
    const float* __restrict__ att, const int* __restrict__ ei,
    float* __restrict__ alpha, float* __restrict__ denom, int E_) {
  const int lane = threadIdx.x & 63;
  const int wave = (blockIdx.x * blockDim.x + threadIdx.x) >> 6;
  const int nwaves = (gridDim.x * blockDim.x) >> 6;
  float we0[4], we1[4], we2[4], at[4];
#pragma unroll
  for (int j = 0; j < 4; ++j) {
    int r = 4 * lane + j;
    we0[j] = We[r * 3 + 0];
    we1[j] = We[r * 3 + 1];
    we2[j] = We[r * 3 + 2];
    at[j] = att[r];
  }
  const float4* xl4 = (const float4*)xl;
  const float4* xr4 = (const float4*)xr;

  int e = wave;
  int src = 0, dst = 0;
  float a0 = 0.f, a1 = 0.f, a2 = 0.f;
  if (e < E_) {
    src = ei[e];
    dst = ei[E_ + e];
    a0 = ea[e * 3 + 0];
    a1 = ea[e * 3 + 1];
    a2 = ea[e * 3 + 2];
  }
  while (e < E_) {
    const int ne = e + nwaves;
    int nsrc = 0, ndst = 0;
    float na0 = 0.f, na1 = 0.f, na2 = 0.f;
    if (ne < E_) {
      nsrc = ei[ne];
      ndst = ei[E_ + ne];
      na0 = ea[ne * 3 + 0];
      na1 = ea[ne * 3 + 1];
      na2 = ea[ne * 3 + 2];
    }
    float4 la = xl4[(size_t)src * 64 + lane];
    float4 ra = xr4[(size_t)dst * 64 + lane];
    float lav[4] = {la.x, la.y, la.z, la.w};
    float rav[4] = {ra.x, ra.y, ra.z, ra.w};
    float p = 0.f;
#pragma unroll
    for (int j = 0; j < 4; ++j) {
      float ev = fmaf(we0[j], a0, fmaf(we1[j], a1, we2[j] * a2));
      float s = lav[j] + rav[j] + ev;
      float z = (s >= 0.f) ? s : 0.2f * s;
      p = fmaf(z, at[j], p);
    }
    p += __shfl_xor(p, 1);
    p += __shfl_xor(p, 2);
    p += __shfl_xor(p, 4);
    p += __shfl_xor(p, 8);
    if ((lane & 15) == 0) {
      int h = lane >> 4;
      float ex = expf(p);  // |logit| << 80: max-subtraction unnecessary
      alpha[e * 4 + h] = ex;
      atomicAdd(&denom[dst * 4 + h], ex);
    }
    e = ne;
    src = nsrc; dst = ndst;
    a0 = na0; a1 = na1; a2 = na2;
  }
}

// ---------------- edge message: acc[dst,c] += (1/4) sum_h a_h * xl[src,h,c]
// One wave per edge, lane = channel c. alpha/denom as single float4 broadcast
// loads; next edge's indices+alpha prefetched.
__global__ __launch_bounds__(256) void edge_msg(
    const float* __restrict__ xl, const float* __restrict__ alpha,
    const float* __restrict__ denom, const int* __restrict__ ei,
    float* __restrict__ acc, int E_) {
  const int lane = threadIdx.x & 63;
  const int wave = (blockIdx.x * blockDim.x + threadIdx.x) >> 6;
  const int nwaves = (gridDim.x * blockDim.x) >> 6;
  const float4* alpha4 = (const float4*)alpha;
  const float4* denom4 = (const float4*)denom;

  int e = wave;
  int src = 0, dst = 0;
  float4 al = {0.f, 0.f, 0.f, 0.f};
  if (e < E_) {
    src = ei[e];
    dst = ei[E_ + e];
    al = alpha4[e];
  }
  while (e < E_) {
    const int ne = e + nwaves;
    int nsrc = 0, ndst = 0;
    float4 nal = {0.f, 0.f, 0.f, 0.f};
    if (ne < E_) {
      nsrc = ei[ne];
      ndst = ei[E_ + ne];
      nal = alpha4[ne];
    }
    float4 dn = denom4[dst];
    float an0 = al.x / (dn.x + 1e-16f);
    float an1 = al.y / (dn.y + 1e-16f);
    float an2 = al.z / (dn.z + 1e-16f);
    float an3 = al.w / (dn.w + 1e-16f);
    const float* xs = xl + (size_t)src * HC;
    float v = an0 * xs[lane] + an1 * xs[64 + lane] + an2 * xs[128 + lane] +
              an3 * xs[192 + lane];
    atomicAdd(&acc[dst * 64 + lane], 0.25f * v);
    e = ne;
    src = nsrc; dst = ndst;
    al = nal;
  }
}

// ---------------- finalize: + bias (and PReLU for layer 2) -----------------
__global__ void finalize(const float* __restrict__ acc, const float* __restrict__ b,
                         float* __restrict__ out, int n) {
  int i = blockIdx.x * blockDim.x + threadIdx.x;
  if (i < n * 64) {
    int c = i & 63;
    out[i] = acc[i] + b[c];
  }
}

__global__ void finalize_prelu(const float* __restrict__ acc, const float* __restrict__ b,
                               const float* __restrict__ pw, float* __restrict__ out, int n) {
  int i = blockIdx.x * blockDim.x + threadIdx.x;
  if (i < n * 64) {
    int c = i & 63;
    float v = acc[i] + b[c];
    out[i] = (v >= 0.f) ? v : pw[c] * v;
  }
}

extern "C" void kernel_launch(void* const* d_in, const int* in_sizes, int n_in,
                              void* d_out, int out_size, void* d_ws, size_t ws_size,
                              hipStream_t stream) {
  const float* x    = (const float*)d_in[0];
  const int*   ei   = (const int*)d_in[1];
  const float* ea   = (const float*)d_in[2];
  const float* Wl1  = (const float*)d_in[3];
  const float* Wr1  = (const float*)d_in[4];
  const float* We1  = (const float*)d_in[5];
  const float* att1 = (const float*)d_in[6];
  const float* b1   = (const float*)d_in[7];
  const float* Wl2  = (const float*)d_in[8];
  const float* Wr2  = (const float*)d_in[9];
  const float* We2  = (const float*)d_in[10];
  const float* att2 = (const float*)d_in[11];
  const float* b2   = (const float*)d_in[12];
  const float* pw   = (const float*)d_in[13];
  const int N_ = in_sizes[0] / 128;
  const int E_ = in_sizes[1] / 2;
  float* out = (float*)d_out;

  char* w = (char*)d_ws;
  auto alloc = [&](size_t bytes) {
    char* p = w;
    w += (bytes + 255) & ~size_t(255);
    return p;
  };
  float* xl    = (float*)alloc((size_t)N_ * HC * 4);
  float* xr    = (float*)alloc((size_t)N_ * HC * 4);
  float* alpha = (float*)alloc((size_t)E_ * 4 * 4);
  float* denom = (float*)alloc((size_t)N_ * 4 * 4);
  float* acc   = (float*)alloc((size_t)N_ * 64 * 4);
  float* hbuf  = (float*)alloc((size_t)N_ * 64 * 4);
  float* WlT1  = (float*)alloc(128 * HC * 4);
  float* WrT1  = (float*)alloc(128 * HC * 4);
  float* WlT2  = (float*)alloc(64 * HC * 4);
  float* WrT2  = (float*)alloc(64 * HC * 4);

  transpose_w<<<(HC * 128 + 255) / 256, 256, 0, stream>>>(Wl1, WlT1, 128);
  transpose_w<<<(HC * 128 + 255) / 256, 256, 0, stream>>>(Wr1, WrT1, 128);
  transpose_w<<<(HC * 64 + 255) / 256, 256, 0, stream>>>(Wl2, WlT2, 64);
  transpose_w<<<(HC * 64 + 255) / 256, 256, 0, stream>>>(Wr2, WrT2, 64);

  const int EB = 2048;  // 8192 waves = 32/CU, grid-stride
  const int GB = (N_ + 15) / 16;

  // ---------------- layer 1 ----------------
  hipMemsetAsync(denom, 0, (size_t)N_ * 4 * 4, stream);
  hipMemsetAsync(acc, 0, (size_t)N_ * 64 * 4, stream);
  gemm_lr<128><<<GB, 256, 0, stream>>>(x, WlT1, WrT1, xl, xr, N_);
  edge_logits<<<EB, 256, 0, stream>>>(xl, xr, ea, We1, att1, ei, alpha, denom, E_);
  edge_msg<<<EB, 256, 0, stream>>>(xl, alpha, denom, ei, acc, E_);
  finalize<<<(N_ * 64 + 255) / 256, 256, 0, stream>>>(acc, b1, hbuf, N_);

  // ---------------- layer 2 ----------------
  hipMemsetAsync(denom, 0, (size_t)N_ * 4 * 4, stream);
  hipMemsetAsync(acc, 0, (size_t)N_ * 64 * 4, stream);
  gemm_lr<64><<<GB, 256, 0, stream>>>(hbuf, WlT2, WrT2, xl, xr, N_);
  edge_logits<<<EB, 256, 0, stream>>>(xl, xr, ea, We2, att2, ei, alpha, denom, E_);
  edge_msg<<<EB, 256, 0, stream>>>(xl, alpha, denom, ei, acc, E_);
  finalize_prelu<<<(N_ * 64 + 255) / 256, 256, 0, stream>>>(acc, b2, pw, out, N_);
}

// Round 3
// 476.324 us; speedup vs baseline: 1.5483x; 1.5162x over previous
//
#include <hip/hip_runtime.h>

#define HEADS 4
#define HID 64
#define HC 256  // HEADS*HID

// ---------------- weight transpose: W [256,F] -> WT [F,256] ----------------
__global__ void transpose_w(const float* __restrict__ W, float* __restrict__ WT, int F) {
  int i = blockIdx.x * blockDim.x + threadIdx.x;
  if (i < HC * F) {
    int r = i / F, k = i - r * F;
    WT[k * HC + r] = W[i];
  }
}

// ---------------- node linear: xl = x@Wl.T, xr = x@Wr.T --------------------
template <int F>
__global__ __launch_bounds__(256) void gemm_lr(const float* __restrict__ xin,
                                               const float* __restrict__ WlT,
                                               const float* __restrict__ WrT,
                                               float* __restrict__ xl,
                                               float* __restrict__ xr, int n_nodes) {
  constexpr int TN = 16;
  __shared__ float xs[TN][F];
  const int node0 = blockIdx.x * TN;
  const int tid = threadIdx.x;
  if (node0 + TN <= n_nodes) {
    const float4* xin4 = (const float4*)xin;
    float4* xs4 = (float4*)(&xs[0][0]);
    for (int i = tid; i < TN * F / 4; i += 256) {
      xs4[i] = xin4[(size_t)node0 * (F / 4) + i];
    }
  } else {
    for (int i = tid; i < TN * F; i += 256) {
      int j = i / F, k = i - j * F;
      int node = node0 + j;
      xs[j][k] = (node < n_nodes) ? xin[node * F + k] : 0.f;
    }
  }
  __syncthreads();

  float accl[TN], accr[TN];
#pragma unroll
  for (int j = 0; j < TN; ++j) { accl[j] = 0.f; accr[j] = 0.f; }

  float wl[4], wr[4];
#pragma unroll
  for (int u = 0; u < 4; ++u) {
    wl[u] = WlT[u * HC + tid];
    wr[u] = WrT[u * HC + tid];
  }

  for (int k = 0; k < F; k += 4) {
    float nwl[4], nwr[4];
    if (k + 4 < F) {
#pragma unroll
      for (int u = 0; u < 4; ++u) {
        nwl[u] = WlT[(k + 4 + u) * HC + tid];
        nwr[u] = WrT[(k + 4 + u) * HC + tid];
      }
    }
#pragma unroll
    for (int j = 0; j < TN; ++j) {
      float4 xv = *(const float4*)&xs[j][k];
      accl[j] = fmaf(wl[0], xv.x, accl[j]);
      accl[j] = fmaf(wl[1], xv.y, accl[j]);
      accl[j] = fmaf(wl[2], xv.z, accl[j]);
      accl[j] = fmaf(wl[3], xv.w, accl[j]);
      accr[j] = fmaf(wr[0], xv.x, accr[j]);
      accr[j] = fmaf(wr[1], xv.y, accr[j]);
      accr[j] = fmaf(wr[2], xv.z, accr[j]);
      accr[j] = fmaf(wr[3], xv.w, accr[j]);
    }
#pragma unroll
    for (int u = 0; u < 4; ++u) {
      wl[u] = nwl[u];
      wr[u] = nwr[u];
    }
  }

#pragma unroll
  for (int j = 0; j < TN; ++j) {
    int node = node0 + j;
    if (node < n_nodes) {
      xl[node * HC + tid] = accl[j];
      xr[node * HC + tid] = accr[j];
    }
  }
}

// ================= CSR build (edges bucketed by dst) =======================
__global__ void k_hist(const int* __restrict__ ei, int* __restrict__ deg, int E_) {
  int e = blockIdx.x * blockDim.x + threadIdx.x;
  if (e < E_) atomicAdd(&deg[ei[E_ + e]], 1);
}

// 256-element block scan: rowstart[i] = exclusive scan within block; partial[b]=block sum
__global__ void k_scan_local(const int* __restrict__ deg, int* __restrict__ rowstart,
                             int* __restrict__ partial, int n) {
  __shared__ int a[256], b[256];
  const int t = threadIdx.x;
  const int i = blockIdx.x * 256 + t;
  const int v = (i < n) ? deg[i] : 0;
  a[t] = v;
  __syncthreads();
  int* cur = a;
  int* nxt = b;
  for (int off = 1; off < 256; off <<= 1) {
    int x = cur[t];
    if (t >= off) x += cur[t - off];
    nxt[t] = x;
    __syncthreads();
    int* tmp = cur; cur = nxt; nxt = tmp;
  }
  const int incl = cur[t];
  if (i < n) rowstart[i] = incl - v;  // exclusive
  if (t == 255) partial[blockIdx.x] = incl;
}

// single-block exclusive scan of the per-block sums (nblk <= 256)
__global__ void k_scan_partial(int* __restrict__ partial, int nblk) {
  __shared__ int a[256], b[256];
  const int t = threadIdx.x;
  const int v = (t < nblk) ? partial[t] : 0;
  a[t] = v;
  __syncthreads();
  int* cur = a;
  int* nxt = b;
  for (int off = 1; off < 256; off <<= 1) {
    int x = cur[t];
    if (t >= off) x += cur[t - off];
    nxt[t] = x;
    __syncthreads();
    int* tmp = cur; cur = nxt; nxt = tmp;
  }
  if (t < nblk) partial[t] = cur[t] - v;  // exclusive
}

__global__ void k_add_off(int* __restrict__ rowstart, const int* __restrict__ partial,
                          int n, int E_) {
  int i = blockIdx.x * blockDim.x + threadIdx.x;
  if (i < n) rowstart[i] += partial[i >> 8];
  if (i == 0) rowstart[n] = E_;
}

__global__ void k_scatter(const int* __restrict__ ei, const float* __restrict__ ea,
                          int* __restrict__ cursor, int* __restrict__ ssrc,
                          float4* __restrict__ sea, int E_) {
  int e = blockIdx.x * blockDim.x + threadIdx.x;
  if (e < E_) {
    int dst = ei[E_ + e];
    int pos = atomicAdd(&cursor[dst], 1);
    ssrc[pos] = ei[e];
    sea[pos] = make_float4(ea[e * 3], ea[e * 3 + 1], ea[e * 3 + 2], 0.f);
  }
}

// ================= fused per-destination attention =========================
// One wave per dst node. Lane l owns channels 4l..4l+3 (head = l/16).
// Online softmax without max-subtraction (|logit| << 80). Gathers xl[src]
// exactly once per edge; bias (+PReLU) fused into epilogue. No atomics.
template <bool PRELU>
__global__ __launch_bounds__(256) void fused_attn(
    const float* __restrict__ xl, const float* __restrict__ xr,
    const int* __restrict__ rowstart, const int* __restrict__ ssrc,
    const float4* __restrict__ sea, const float* __restrict__ We,
    const float* __restrict__ att, const float* __restrict__ bias,
    const float* __restrict__ pw, float* __restrict__ out, int n) {
  const int lane = threadIdx.x & 63;
  const int d = (blockIdx.x * blockDim.x + threadIdx.x) >> 6;
  if (d >= n) return;
  float we0[4], we1[4], we2[4], at[4];
#pragma unroll
  for (int j = 0; j < 4; ++j) {
    int r = 4 * lane + j;
    we0[j] = We[r * 3 + 0];
    we1[j] = We[r * 3 + 1];
    we2[j] = We[r * 3 + 2];
    at[j] = att[r];
  }
  const float4* xl4 = (const float4*)xl;
  const float4 xrv = ((const float4*)xr)[(size_t)d * 64 + lane];

  int pos = rowstart[d];
  const int end = rowstart[d + 1];
  float4 num = {0.f, 0.f, 0.f, 0.f};
  float den = 0.f;

  float4 eav = {0.f, 0.f, 0.f, 0.f};
  float4 la = {0.f, 0.f, 0.f, 0.f};
  if (pos < end) {
    int src = ssrc[pos];
    eav = sea[pos];
    la = xl4[(size_t)src * 64 + lane];
  }
  while (pos < end) {
    const int npos = pos + 1;
    float4 neav = eav;
    float4 nla = la;
    if (npos < end) {
      int nsrc = ssrc[npos];
      neav = sea[npos];
      nla = xl4[(size_t)nsrc * 64 + lane];
    }
    float lav[4] = {la.x, la.y, la.z, la.w};
    float xrl[4] = {xrv.x, xrv.y, xrv.z, xrv.w};
    float p = 0.f;
#pragma unroll
    for (int j = 0; j < 4; ++j) {
      float ev = fmaf(we0[j], eav.x, fmaf(we1[j], eav.y, we2[j] * eav.z));
      float s = lav[j] + xrl[j] + ev;
      float z = (s >= 0.f) ? s : 0.2f * s;
      p = fmaf(z, at[j], p);
    }
    p += __shfl_xor(p, 1);
    p += __shfl_xor(p, 2);
    p += __shfl_xor(p, 4);
    p += __shfl_xor(p, 8);
    const float w = __expf(p);
    den += w;
    num.x = fmaf(w, la.x, num.x);
    num.y = fmaf(w, la.y, num.y);
    num.z = fmaf(w, la.z, num.z);
    num.w = fmaf(w, la.w, num.w);
    pos = npos;
    eav = neav;
    la = nla;
  }

  const float inv = 1.f / (den + 1e-16f);
  float4 r;
  r.x = num.x * inv;
  r.y = num.y * inv;
  r.z = num.z * inv;
  r.w = num.w * inv;
  // combine the 4 heads: lanes {m, m+16, m+32, m+48} hold the same channels
  r.x += __shfl_xor(r.x, 16);
  r.y += __shfl_xor(r.y, 16);
  r.z += __shfl_xor(r.z, 16);
  r.w += __shfl_xor(r.w, 16);
  r.x += __shfl_xor(r.x, 32);
  r.y += __shfl_xor(r.y, 32);
  r.z += __shfl_xor(r.z, 32);
  r.w += __shfl_xor(r.w, 32);
  if (lane < 16) {
    const int c = 4 * lane;
    float4 o;
    o.x = 0.25f * r.x + bias[c + 0];
    o.y = 0.25f * r.y + bias[c + 1];
    o.z = 0.25f * r.z + bias[c + 2];
    o.w = 0.25f * r.w + bias[c + 3];
    if (PRELU) {
      o.x = (o.x >= 0.f) ? o.x : pw[c + 0] * o.x;
      o.y = (o.y >= 0.f) ? o.y : pw[c + 1] * o.y;
      o.z = (o.z >= 0.f) ? o.z : pw[c + 2] * o.z;
      o.w = (o.w >= 0.f) ? o.w : pw[c + 3] * o.w;
    }
    ((float4*)out)[(size_t)d * 16 + lane] = o;
  }
}

extern "C" void kernel_launch(void* const* d_in, const int* in_sizes, int n_in,
                              void* d_out, int out_size, void* d_ws, size_t ws_size,
                              hipStream_t stream) {
  const float* x    = (const float*)d_in[0];
  const int*   ei   = (const int*)d_in[1];
  const float* ea   = (const float*)d_in[2];
  const float* Wl1  = (const float*)d_in[3];
  const float* Wr1  = (const float*)d_in[4];
  const float* We1  = (const float*)d_in[5];
  const float* att1 = (const float*)d_in[6];
  const float* b1   = (const float*)d_in[7];
  const float* Wl2  = (const float*)d_in[8];
  const float* Wr2  = (const float*)d_in[9];
  const float* We2  = (const float*)d_in[10];
  const float* att2 = (const float*)d_in[11];
  const float* b2   = (const float*)d_in[12];
  const float* pw   = (const float*)d_in[13];
  const int N_ = in_sizes[0] / 128;
  const int E_ = in_sizes[1] / 2;
  float* out = (float*)d_out;

  char* w = (char*)d_ws;
  auto alloc = [&](size_t bytes) {
    char* p = w;
    w += (bytes + 255) & ~size_t(255);
    return p;
  };
  float*  xl       = (float*)alloc((size_t)N_ * HC * 4);
  float*  xr       = (float*)alloc((size_t)N_ * HC * 4);
  float*  hbuf     = (float*)alloc((size_t)N_ * 64 * 4);
  int*    ssrc     = (int*)alloc((size_t)E_ * 4);
  float4* sea      = (float4*)alloc((size_t)E_ * 16);
  int*    deg      = (int*)alloc((size_t)N_ * 4);
  int*    rowstart = (int*)alloc((size_t)(N_ + 1) * 4);
  int*    cursor   = (int*)alloc((size_t)N_ * 4);
  int*    partial  = (int*)alloc(256 * 4);
  float*  WlT1     = (float*)alloc(128 * HC * 4);
  float*  WrT1     = (float*)alloc(128 * HC * 4);
  float*  WlT2     = (float*)alloc(64 * HC * 4);
  float*  WrT2     = (float*)alloc(64 * HC * 4);

  transpose_w<<<(HC * 128 + 255) / 256, 256, 0, stream>>>(Wl1, WlT1, 128);
  transpose_w<<<(HC * 128 + 255) / 256, 256, 0, stream>>>(Wr1, WrT1, 128);
  transpose_w<<<(HC * 64 + 255) / 256, 256, 0, stream>>>(Wl2, WlT2, 64);
  transpose_w<<<(HC * 64 + 255) / 256, 256, 0, stream>>>(Wr2, WrT2, 64);

  // ---- CSR build (once; shared by both layers) ----
  const int nblk = (N_ + 255) / 256;
  hipMemsetAsync(deg, 0, (size_t)N_ * 4, stream);
  k_hist<<<(E_ + 255) / 256, 256, 0, stream>>>(ei, deg, E_);
  k_scan_local<<<nblk, 256, 0, stream>>>(deg, rowstart, partial, N_);
  k_scan_partial<<<1, 256, 0, stream>>>(partial, nblk);
  k_add_off<<<nblk, 256, 0, stream>>>(rowstart, partial, N_, E_);
  hipMemcpyAsync(cursor, rowstart, (size_t)N_ * 4, hipMemcpyDeviceToDevice, stream);
  k_scatter<<<(E_ + 255) / 256, 256, 0, stream>>>(ei, ea, cursor, ssrc, sea, E_);

  const int GB = (N_ + 15) / 16;
  const int FB = (N_ + 3) / 4;  // fused: one wave per dst node

  // ---- layer 1 ----
  gemm_lr<128><<<GB, 256, 0, stream>>>(x, WlT1, WrT1, xl, xr, N_);
  fused_attn<false><<<FB, 256, 0, stream>>>(xl, xr, rowstart, ssrc, sea, We1, att1,
                                            b1, pw, hbuf, N_);
  // ---- layer 2 ----
  gemm_lr<64><<<GB, 256, 0, stream>>>(hbuf, WlT2, WrT2, xl, xr, N_);
  fused_attn<true><<<FB, 256, 0, stream>>>(xl, xr, rowstart, ssrc, sea, We2, att2,
                                           b2, pw, out, N_);
}

// Round 4
// 391.958 us; speedup vs baseline: 1.8815x; 1.2152x over previous
//
#include <hip/hip_runtime.h>
#include <hip/hip_bf16.h>

#define HC 256

typedef __attribute__((ext_vector_type(8))) short bf16x8;
typedef __attribute__((ext_vector_type(4))) float f32x4;

// ======== split fp32 -> (hi|lo) bf16, K-concat layouts =====================
// A2[row][2F]: cols [0,F)=hi, [F,2F)=lo
__global__ void k_split_x(const float* __restrict__ x, ushort* __restrict__ A2,
                          int n, int F) {
  int idx = blockIdx.x * blockDim.x + threadIdx.x;  // one per 4 elements
  int total = n * F / 4;
  if (idx >= total) return;
  int fq = F / 4;
  int row = idx / fq, q = idx - row * fq;
  float4 v = ((const float4*)x)[idx];
  float vv[4] = {v.x, v.y, v.z, v.w};
  ushort hb[4], lb[4];
#pragma unroll
  for (int j = 0; j < 4; ++j) {
    __hip_bfloat16 h = __float2bfloat16(vv[j]);
    hb[j] = *(ushort*)&h;
    __hip_bfloat16 l = __float2bfloat16(vv[j] - __bfloat162float(h));
    lb[j] = *(ushort*)&l;
  }
  ushort* rp = A2 + (size_t)row * 2 * F;
  *(ushort4*)(rp + q * 4) = make_ushort4(hb[0], hb[1], hb[2], hb[3]);
  *(ushort4*)(rp + F + q * 4) = make_ushort4(lb[0], lb[1], lb[2], lb[3]);
}

// WT[col][3F]: col<256 from Wl, col>=256 from Wr; k-blocks hi|lo|hi
__global__ void k_split_w(const float* __restrict__ Wl, const float* __restrict__ Wr,
                          ushort* __restrict__ WT, int F) {
  int idx = blockIdx.x * blockDim.x + threadIdx.x;
  if (idx >= 512 * F) return;
  int col = idx / F, f = idx - col * F;
  float v = (col < 256) ? Wl[col * F + f] : Wr[(col - 256) * F + f];
  __hip_bfloat16 h = __float2bfloat16(v);
  __hip_bfloat16 l = __float2bfloat16(v - __bfloat162float(h));
  ushort* row = WT + (size_t)col * 3 * F;
  row[f] = *(ushort*)&h;
  row[F + f] = *(ushort*)&l;
  row[2 * F + f] = *(ushort*)&h;
}

// ======== MFMA GEMM: xlr[M][512] = A2 (split) x WT (split) ================
// D = A_hi*B_hi + A_hi*B_lo + A_lo*B_hi via K-concat (Khat = 3F).
// Block: 256 thr = 4 waves; tile 128(M) x 128(N), BK=32. Wave owns 32x128.
// LDS pitch 40 ushorts (+8 pad) -> 2-way max on frag ds_read_b128 (free).
template <int F>
__global__ __launch_bounds__(256) void gemm_mfma(const ushort* __restrict__ A2,
                                                 const ushort* __restrict__ WT,
                                                 float* __restrict__ xlr, int n_nodes) {
  constexpr int KC = 3 * F;
  constexpr int NSTEP = KC / 32;
  constexpr int PITCH = 40;
  __shared__ __align__(16) ushort As[128 * PITCH];
  __shared__ __align__(16) ushort Bs[128 * PITCH];
  const int tid = threadIdx.x;
  const int wv = tid >> 6, lane = tid & 63;
  const int m16 = lane & 15, quad = lane >> 4;
  const int row0 = blockIdx.x * 128;
  const int col0 = blockIdx.y * 128;

  f32x4 acc[2][8];
#pragma unroll
  for (int i = 0; i < 2; ++i)
#pragma unroll
    for (int j = 0; j < 8; ++j) acc[i][j] = (f32x4){0.f, 0.f, 0.f, 0.f};

  for (int s = 0; s < NSTEP; ++s) {
    const int khat = s * 32;
    // A source col within A2's [hi(F)|lo(F)] row:
    //   khat<F -> hi@khat ; F<=khat<2F -> hi@khat-F ; khat>=2F -> lo@F+(khat-2F)
    // both latter cases equal khat-F.
    const int asrc = (khat < F) ? khat : khat - F;
    __syncthreads();
#pragma unroll
    for (int c = 0; c < 2; ++c) {
      int u = tid + 256 * c;     // 512 16B-chunks per tile
      int r = u >> 2, ch = u & 3;
      int grow = row0 + r;
      int4 aval = {0, 0, 0, 0};
      if (grow < n_nodes)
        aval = *(const int4*)(A2 + (size_t)grow * (2 * F) + asrc + ch * 8);
      *(int4*)&As[r * PITCH + ch * 8] = aval;
      int4 bval = *(const int4*)(WT + (size_t)(col0 + r) * KC + khat + ch * 8);
      *(int4*)&Bs[r * PITCH + ch * 8] = bval;
    }
    __syncthreads();
    bf16x8 af[2];
#pragma unroll
    for (int i = 0; i < 2; ++i)
      af[i] = *(bf16x8*)&As[(wv * 32 + i * 16 + m16) * PITCH + quad * 8];
#pragma unroll
    for (int j = 0; j < 8; ++j) {
      bf16x8 bf = *(bf16x8*)&Bs[(j * 16 + m16) * PITCH + quad * 8];
      acc[0][j] = __builtin_amdgcn_mfma_f32_16x16x32_bf16(af[0], bf, acc[0][j], 0, 0, 0);
      acc[1][j] = __builtin_amdgcn_mfma_f32_16x16x32_bf16(af[1], bf, acc[1][j], 0, 0, 0);
    }
  }
  // epilogue: C/D layout col=lane&15, row=quad*4+reg
#pragma unroll
  for (int i = 0; i < 2; ++i) {
#pragma unroll
    for (int r = 0; r < 4; ++r) {
      int grow = row0 + wv * 32 + i * 16 + quad * 4 + r;
      if (grow < n_nodes) {
#pragma unroll
        for (int j = 0; j < 8; ++j)
          xlr[(size_t)grow * 512 + col0 + j * 16 + m16] = acc[i][j][r];
      }
    }
  }
}

// ================= CSR build (edges bucketed by dst) =======================
__global__ void k_hist(const int* __restrict__ ei, int* __restrict__ deg, int E_) {
  int e = blockIdx.x * blockDim.x + threadIdx.x;
  if (e < E_) atomicAdd(&deg[ei[E_ + e]], 1);
}

__global__ void k_scan_local(const int* __restrict__ deg, int* __restrict__ rowstart,
                             int* __restrict__ partial, int n) {
  __shared__ int a[256], b[256];
  const int t = threadIdx.x;
  const int i = blockIdx.x * 256 + t;
  const int v = (i < n) ? deg[i] : 0;
  a[t] = v;
  __syncthreads();
  int* cur = a;
  int* nxt = b;
  for (int off = 1; off < 256; off <<= 1) {
    int x = cur[t];
    if (t >= off) x += cur[t - off];
    nxt[t] = x;
    __syncthreads();
    int* tmp = cur; cur = nxt; nxt = tmp;
  }
  const int incl = cur[t];
  if (i < n) rowstart[i] = incl - v;
  if (t == 255) partial[blockIdx.x] = incl;
}

__global__ void k_scan_partial(int* __restrict__ partial, int nblk) {
  __shared__ int a[256], b[256];
  const int t = threadIdx.x;
  const int v = (t < nblk) ? partial[t] : 0;
  a[t] = v;
  __syncthreads();
  int* cur = a;
  int* nxt = b;
  for (int off = 1; off < 256; off <<= 1) {
    int x = cur[t];
    if (t >= off) x += cur[t - off];
    nxt[t] = x;
    __syncthreads();
    int* tmp = cur; cur = nxt; nxt = tmp;
  }
  if (t < nblk) partial[t] = cur[t] - v;
}

__global__ void k_add_off(int* __restrict__ rowstart, const int* __restrict__ partial,
                          int n, int E_) {
  int i = blockIdx.x * blockDim.x + threadIdx.x;
  if (i < n) rowstart[i] += partial[i >> 8];
  if (i == 0) rowstart[n] = E_;
}

__global__ void k_scatter(const int* __restrict__ ei, const float* __restrict__ ea,
                          int* __restrict__ cursor, int* __restrict__ ssrc,
                          float4* __restrict__ sea, int E_) {
  int e = blockIdx.x * blockDim.x + threadIdx.x;
  if (e < E_) {
    int dst = ei[E_ + e];
    int pos = atomicAdd(&cursor[dst], 1);
    ssrc[pos] = ei[e];
    sea[pos] = make_float4(ea[e * 3], ea[e * 3 + 1], ea[e * 3 + 2], 0.f);
  }
}

// ================= fused per-destination attention =========================
// xlr[n][512]: cols 0..255 = xl, 256..511 = xr. One wave per dst node.
template <bool PRELU>
__global__ __launch_bounds__(256) void fused_attn(
    const float* __restrict__ xlr, const int* __restrict__ rowstart,
    const int* __restrict__ ssrc, const float4* __restrict__ sea,
    const float* __restrict__ We, const float* __restrict__ att,
    const float* __restrict__ bias, const float* __restrict__ pw,
    float* __restrict__ out, int n) {
  const int lane = threadIdx.x & 63;
  const int d = (blockIdx.x * blockDim.x + threadIdx.x) >> 6;
  if (d >= n) return;
  float we0[4], we1[4], we2[4], at[4];
#pragma unroll
  for (int j = 0; j < 4; ++j) {
    int r = 4 * lane + j;
    we0[j] = We[r * 3 + 0];
    we1[j] = We[r * 3 + 1];
    we2[j] = We[r * 3 + 2];
    at[j] = att[r];
  }
  const float4* xl4 = (const float4*)xlr;
  const float4 xrv = xl4[(size_t)d * 128 + 64 + lane];

  int pos = rowstart[d];
  const int end = rowstart[d + 1];
  float4 num = {0.f, 0.f, 0.f, 0.f};
  float den = 0.f;

  float4 eav = {0.f, 0.f, 0.f, 0.f};
  float4 la = {0.f, 0.f, 0.f, 0.f};
  if (pos < end) {
    int src = ssrc[pos];
    eav = sea[pos];
    la = xl4[(size_t)src * 128 + lane];
  }
  while (pos < end) {
    const int npos = pos + 1;
    float4 neav = eav;
    float4 nla = la;
    if (npos < end) {
      int nsrc = ssrc[npos];
      neav = sea[npos];
      nla = xl4[(size_t)nsrc * 128 + lane];
    }
    float lav[4] = {la.x, la.y, la.z, la.w};
    float xrl[4] = {xrv.x, xrv.y, xrv.z, xrv.w};
    float p = 0.f;
#pragma unroll
    for (int j = 0; j < 4; ++j) {
      float ev = fmaf(we0[j], eav.x, fmaf(we1[j], eav.y, we2[j] * eav.z));
      float s = lav[j] + xrl[j] + ev;
      float z = (s >= 0.f) ? s : 0.2f * s;
      p = fmaf(z, at[j], p);
    }
    p += __shfl_xor(p, 1);
    p += __shfl_xor(p, 2);
    p += __shfl_xor(p, 4);
    p += __shfl_xor(p, 8);
    const float w = __expf(p);  // |logit| << 80: no max-subtraction needed
    den += w;
    num.x = fmaf(w, la.x, num.x);
    num.y = fmaf(w, la.y, num.y);
    num.z = fmaf(w, la.z, num.z);
    num.w = fmaf(w, la.w, num.w);
    pos = npos;
    eav = neav;
    la = nla;
  }

  const float inv = 1.f / (den + 1e-16f);
  float4 r;
  r.x = num.x * inv;
  r.y = num.y * inv;
  r.z = num.z * inv;
  r.w = num.w * inv;
  r.x += __shfl_xor(r.x, 16);
  r.y += __shfl_xor(r.y, 16);
  r.z += __shfl_xor(r.z, 16);
  r.w += __shfl_xor(r.w, 16);
  r.x += __shfl_xor(r.x, 32);
  r.y += __shfl_xor(r.y, 32);
  r.z += __shfl_xor(r.z, 32);
  r.w += __shfl_xor(r.w, 32);
  if (lane < 16) {
    const int c = 4 * lane;
    float4 o;
    o.x = 0.25f * r.x + bias[c + 0];
    o.y = 0.25f * r.y + bias[c + 1];
    o.z = 0.25f * r.z + bias[c + 2];
    o.w = 0.25f * r.w + bias[c + 3];
    if (PRELU) {
      o.x = (o.x >= 0.f) ? o.x : pw[c + 0] * o.x;
      o.y = (o.y >= 0.f) ? o.y : pw[c + 1] * o.y;
      o.z = (o.z >= 0.f) ? o.z : pw[c + 2] * o.z;
      o.w = (o.w >= 0.f) ? o.w : pw[c + 3] * o.w;
    }
    ((float4*)out)[(size_t)d * 16 + lane] = o;
  }
}

extern "C" void kernel_launch(void* const* d_in, const int* in_sizes, int n_in,
                              void* d_out, int out_size, void* d_ws, size_t ws_size,
                              hipStream_t stream) {
  const float* x    = (const float*)d_in[0];
  const int*   ei   = (const int*)d_in[1];
  const float* ea   = (const float*)d_in[2];
  const float* Wl1  = (const float*)d_in[3];
  const float* Wr1  = (const float*)d_in[4];
  const float* We1  = (const float*)d_in[5];
  const float* att1 = (const float*)d_in[6];
  const float* b1   = (const float*)d_in[7];
  const float* Wl2  = (const float*)d_in[8];
  const float* Wr2  = (const float*)d_in[9];
  const float* We2  = (const float*)d_in[10];
  const float* att2 = (const float*)d_in[11];
  const float* b2   = (const float*)d_in[12];
  const float* pw   = (const float*)d_in[13];
  const int N_ = in_sizes[0] / 128;
  const int E_ = in_sizes[1] / 2;
  float* out = (float*)d_out;

  char* w = (char*)d_ws;
  auto alloc = [&](size_t bytes) {
    char* p = w;
    w += (bytes + 255) & ~size_t(255);
    return p;
  };
  float*  xlr      = (float*)alloc((size_t)N_ * 512 * 4);     // xl | xr
  ushort* A2       = (ushort*)alloc((size_t)N_ * 256 * 2);    // split input (covers F=128)
  float*  hbuf     = (float*)alloc((size_t)N_ * 64 * 4);
  int*    ssrc     = (int*)alloc((size_t)E_ * 4);
  float4* sea      = (float4*)alloc((size_t)E_ * 16);
  int*    deg      = (int*)alloc((size_t)N_ * 4);
  int*    rowstart = (int*)alloc((size_t)(N_ + 1) * 4);
  int*    cursor   = (int*)alloc((size_t)N_ * 4);
  int*    partial  = (int*)alloc(256 * 4);
  ushort* WT1      = (ushort*)alloc((size_t)512 * 384 * 2);
  ushort* WT2      = (ushort*)alloc((size_t)512 * 192 * 2);

  // ---- weight splits ----
  k_split_w<<<(512 * 128 + 255) / 256, 256, 0, stream>>>(Wl1, Wr1, WT1, 128);
  k_split_w<<<(512 * 64 + 255) / 256, 256, 0, stream>>>(Wl2, Wr2, WT2, 64);

  // ---- CSR build (once; shared by both layers) ----
  const int nblk = (N_ + 255) / 256;
  hipMemsetAsync(deg, 0, (size_t)N_ * 4, stream);
  k_hist<<<(E_ + 255) / 256, 256, 0, stream>>>(ei, deg, E_);
  k_scan_local<<<nblk, 256, 0, stream>>>(deg, rowstart, partial, N_);
  k_scan_partial<<<1, 256, 0, stream>>>(partial, nblk);
  k_add_off<<<nblk, 256, 0, stream>>>(rowstart, partial, N_, E_);
  hipMemcpyAsync(cursor, rowstart, (size_t)N_ * 4, hipMemcpyDeviceToDevice, stream);
  k_scatter<<<(E_ + 255) / 256, 256, 0, stream>>>(ei, ea, cursor, ssrc, sea, E_);

  const dim3 GG((N_ + 127) / 128, 4);
  const int FB = (N_ + 3) / 4;  // fused: one wave per dst node

  // ---- layer 1 ----
  k_split_x<<<(N_ * 128 / 4 + 255) / 256, 256, 0, stream>>>(x, A2, N_, 128);
  gemm_mfma<128><<<GG, 256, 0, stream>>>(A2, WT1, xlr, N_);
  fused_attn<false><<<FB, 256, 0, stream>>>(xlr, rowstart, ssrc, sea, We1, att1,
                                            b1, pw, hbuf, N_);
  // ---- layer 2 ----
  k_split_x<<<(N_ * 64 / 4 + 255) / 256, 256, 0, stream>>>(hbuf, A2, N_, 64);
  gemm_mfma<64><<<GG, 256, 0, stream>>>(A2, WT2, xlr, N_);
  fused_attn<true><<<FB, 256, 0, stream>>>(xlr, rowstart, ssrc, sea, We2, att2,
                                           b2, pw, out, N_);
}